// Round 3
// baseline (931.302 us; speedup 1.0000x reference)
//
#include <hip/hip_runtime.h>
#include <stdint.h>

constexpr int   kB  = 4;
constexpr int   kNS = 4096;
constexpr int   kVP = 2562;
constexpr int   kFP = 5120;
constexpr int   kVG = 6890;
constexpr int   kFG = 13776;
constexpr float kEPS  = 1e-12f;
constexpr float kTINY = 1.17549435e-38f;

// ---------------- Threefry-2x32 (exact JAX semantics) ----------------
__host__ __device__ inline void tf2x32(uint32_t k0, uint32_t k1,
                                       uint32_t& x0r, uint32_t& x1r) {
  uint32_t ks2 = k0 ^ k1 ^ 0x1BD11BDAu;
  uint32_t x0 = x0r + k0, x1 = x1r + k1;
#define TF_R(r) { x0 += x1; x1 = (x1 << (r)) | (x1 >> (32 - (r))); x1 ^= x0; }
  TF_R(13) TF_R(15) TF_R(26) TF_R(6)
  x0 += k1;  x1 += ks2 + 1u;
  TF_R(17) TF_R(29) TF_R(16) TF_R(24)
  x0 += ks2; x1 += k0 + 2u;
  TF_R(13) TF_R(15) TF_R(26) TF_R(6)
  x0 += k0;  x1 += k1 + 3u;
  TF_R(17) TF_R(29) TF_R(16) TF_R(24)
  x0 += k1;  x1 += ks2 + 4u;
  TF_R(13) TF_R(15) TF_R(26) TF_R(6)
  x0 += ks2; x1 += k0 + 5u;
#undef TF_R
  x0r = x0; x1r = x1;
}

__device__ inline float bits_to_unit(uint32_t b) {
  // JAX: bitcast((b>>9)|0x3f800000) - 1.0  ->  [0,1)
  return __uint_as_float((b >> 9) | 0x3f800000u) - 1.0f;
}

// faces may arrive as int32 (documented) or int64 (reference dtype). For
// int64 little-endian with values < 2^31, every odd 32-bit word is 0.
// P(false positive with real int32 indices) ~ (1/V)^4 ~ 1e-14.
__device__ inline int faces_is64(const int* __restrict__ faces) {
  return (faces[1] == 0 && faces[3] == 0 && faces[5] == 0 && faces[7] == 0) ? 1 : 0;
}
__device__ inline int face_vtx(const int* __restrict__ faces, int f, int c,
                               int is64, int V) {
  int e = f * 3 + c;
  int v = faces[is64 ? (e << 1) : e];
  // clamp defensively: a bad index must never fault
  return v < 0 ? 0 : (v >= V ? V - 1 : v);
}

// ---------------- trivial diagnostic kernel ----------------
__global__ void mlk_write_scalar(float* out, float val) {
  if (threadIdx.x == 0 && blockIdx.x == 0) out[0] = val;
}

// ---------------- face geometry: 1/(area+eps) and normals ----------------
__global__ __launch_bounds__(256) void mlk_prep_faces(
    const float* __restrict__ verts, const int* __restrict__ faces,
    int V, int F, float* __restrict__ inv_a, float* __restrict__ fnrm) {
  int idx = blockIdx.x * 256 + threadIdx.x;
  if (idx >= kB * F) return;
  int is64 = faces_is64(faces);
  int b = idx / F, f = idx - b * F;
  int i0 = face_vtx(faces, f, 0, is64, V);
  int i1 = face_vtx(faces, f, 1, is64, V);
  int i2 = face_vtx(faces, f, 2, is64, V);
  const float* vb = verts + (size_t)b * V * 3;
  float ax = vb[i0*3+0], ay = vb[i0*3+1], az = vb[i0*3+2];
  float bx = vb[i1*3+0], by = vb[i1*3+1], bz = vb[i1*3+2];
  float cx = vb[i2*3+0], cy = vb[i2*3+1], cz = vb[i2*3+2];
  float e1x = bx-ax, e1y = by-ay, e1z = bz-az;
  float e2x = cx-ax, e2y = cy-ay, e2z = cz-az;
  float nx = e1y*e2z - e1z*e2y;
  float ny = e1z*e2x - e1x*e2z;
  float nz = e1x*e2y - e1y*e2x;
  float area2 = sqrtf(nx*nx + ny*ny + nz*nz);   // 2*area
  inv_a[idx] = 1.0f / (0.5f*area2 + kEPS);
  float inv_n = 1.0f / (area2 + kEPS);
  fnrm[3*idx+0] = nx*inv_n;
  fnrm[3*idx+1] = ny*inv_n;
  fnrm[3*idx+2] = nz*inv_n;
}

// ---------------- categorical sampling (Gumbel argmax, exact bits) ----------------
// One block handles sample-rows w and w+8192 (threefry pair).
// argmax_f(gumbel + log a) == argmin_f((-log2 u) * inv_a), first-index ties.
__global__ __launch_bounds__(256) void mlk_cat_sample(
    const float* __restrict__ inv_a, int F,
    uint32_t kf0, uint32_t kf1, int* __restrict__ face_idx) {
  int w = blockIdx.x;            // 0..8191
  int tid = threadIdx.x;
  int b1 = w >> 12;              // w / kNS
  int s  = w & (kNS - 1);
  int b2 = b1 + 2;
  const float* ia1 = inv_a + b1 * F;
  const float* ia2 = inv_a + b2 * F;
  uint32_t base0 = (uint32_t)w * (uint32_t)F;
  uint32_t basep = (uint32_t)(w + 8192) * (uint32_t)F;
  float best0 = INFINITY, best1 = INFINITY;
  int bi0 = 0, bi1 = 0;
  for (int f = tid; f < F; f += 256) {
    uint32_t x0 = base0 + (uint32_t)f;
    uint32_t x1 = basep + (uint32_t)f;
    tf2x32(kf0, kf1, x0, x1);
    float u0 = bits_to_unit(x0); if (u0 == 0.0f) u0 = kTINY;
    float u1 = bits_to_unit(x1); if (u1 == 0.0f) u1 = kTINY;
    float s0 = -__log2f(u0) * ia1[f];
    float s1 = -__log2f(u1) * ia2[f];
    if (s0 < best0) { best0 = s0; bi0 = f; }
    if (s1 < best1) { best1 = s1; bi1 = f; }
  }
  __shared__ float sv0[256], sv1[256];
  __shared__ int   si0[256], si1[256];
  sv0[tid] = best0; si0[tid] = bi0;
  sv1[tid] = best1; si1[tid] = bi1;
  __syncthreads();
  for (int off = 128; off > 0; off >>= 1) {
    if (tid < off) {
      if (sv0[tid+off] < sv0[tid] ||
          (sv0[tid+off] == sv0[tid] && si0[tid+off] < si0[tid])) {
        sv0[tid] = sv0[tid+off]; si0[tid] = si0[tid+off];
      }
      if (sv1[tid+off] < sv1[tid] ||
          (sv1[tid+off] == sv1[tid] && si1[tid+off] < si1[tid])) {
        sv1[tid] = sv1[tid+off]; si1[tid] = si1[tid+off];
      }
    }
    __syncthreads();
  }
  if (tid == 0) {
    face_idx[b1 * kNS + s] = si0[0];
    face_idx[b2 * kNS + s] = si1[0];
  }
}

// ---------------- barycentric point generation ----------------
__global__ __launch_bounds__(256) void mlk_gen_points(
    const float* __restrict__ verts, const int* __restrict__ faces,
    const float* __restrict__ fnrm, const int* __restrict__ face_idx,
    int V, int F,
    uint32_t ku0, uint32_t ku1, uint32_t kv0, uint32_t kv1,
    float* __restrict__ pts, float* __restrict__ pnrm) {
  int t = blockIdx.x * 256 + threadIdx.x;   // 0..8191
  if (t >= 8192) return;
  int is64 = faces_is64(faces);
  uint32_t ux0 = (uint32_t)t, ux1 = (uint32_t)(t + 8192);
  tf2x32(ku0, ku1, ux0, ux1);
  uint32_t vx0 = (uint32_t)t, vx1 = (uint32_t)(t + 8192);
  tf2x32(kv0, kv1, vx0, vx1);
#pragma unroll
  for (int half = 0; half < 2; ++half) {
    int i = t + half * 8192;                    // flat (b*kNS+s)
    float u = bits_to_unit(half ? ux1 : ux0);
    float v = bits_to_unit(half ? vx1 : vx0);
    int b = i >> 12;
    int fid = face_idx[i];
    fid = fid < 0 ? 0 : (fid >= F ? F - 1 : fid);
    const float* vb = verts + (size_t)b * V * 3;
    int i0 = face_vtx(faces, fid, 0, is64, V);
    int i1 = face_vtx(faces, fid, 1, is64, V);
    int i2 = face_vtx(faces, fid, 2, is64, V);
    float r1 = sqrtf(u);
    float w0 = 1.0f - r1, w1 = r1 * (1.0f - v), w2 = r1 * v;
#pragma unroll
    for (int c = 0; c < 3; ++c) {
      pts[i*3+c] = w0 * vb[i0*3+c] + w1 * vb[i1*3+c] + w2 * vb[i2*3+c];
      pnrm[i*3+c] = fnrm[((size_t)b*F + fid)*3 + c];
    }
  }
}

// ---------------- chamfer: per query point min over reference set ----------------
__global__ __launch_bounds__(256) void mlk_chamfer(
    const float* __restrict__ qpts, const float* __restrict__ rpts,
    float* __restrict__ minv, int* __restrict__ mini) {
  constexpr int TILE = 1024;     // 12 KB LDS
  __shared__ float lp[TILE * 3];
  int b = blockIdx.x >> 4;       // 16 blocks per batch
  int n = (blockIdx.x & 15) * 256 + threadIdx.x;
  int gi = b * kNS + n;
  float px = qpts[gi*3+0], py = qpts[gi*3+1], pz = qpts[gi*3+2];
  const float* rb = rpts + (size_t)b * kNS * 3;
  float best = INFINITY; int bidx = 0;
  for (int t0 = 0; t0 < kNS; t0 += TILE) {
    __syncthreads();
    for (int i = threadIdx.x; i < TILE * 3; i += 256) lp[i] = rb[t0*3 + i];
    __syncthreads();
    for (int m = 0; m < TILE; ++m) {
      float dx = px - lp[m*3+0];
      float dy = py - lp[m*3+1];
      float dz = pz - lp[m*3+2];
      float d2 = dx*dx + dy*dy + dz*dz;
      if (d2 < best) { best = d2; bidx = t0 + m; }
    }
  }
  minv[gi] = best;
  if (mini) mini[gi] = bidx;
}

// ---------------- finalize: means + normal loss + edge loss ----------------
__global__ __launch_bounds__(256) void mlk_reduce_loss(
    const float* __restrict__ min_p2g, const float* __restrict__ min_g2p,
    const float* __restrict__ pred_nrm, const float* __restrict__ gt_nrm,
    const int* __restrict__ idx_p2g,
    const float* __restrict__ pverts, const int* __restrict__ pfaces,
    float* __restrict__ out) {
  int tid = threadIdx.x;
  int is64 = faces_is64(pfaces);
  float s1 = 0.f, s2 = 0.f, sc = 0.f, se = 0.f;
  for (int i = tid; i < kB * kNS; i += 256) {
    s1 += min_p2g[i];
    s2 += min_g2p[i];
    int b = i >> 12;
    int m = idx_p2g[i];
    m = m < 0 ? 0 : (m >= kNS ? kNS - 1 : m);
    const float* pn = pred_nrm + (size_t)i * 3;
    const float* gn = gt_nrm + ((size_t)b * kNS + m) * 3;
    sc += fabsf(pn[0]*gn[0] + pn[1]*gn[1] + pn[2]*gn[2]);
  }
  for (int e = tid; e < kB * kFP * 3; e += 256) {
    int b = e / (kFP * 3);
    int r = e - b * kFP * 3;
    int f = r / 3, k = r - f * 3;
    int ia, ib;
    if (k == 0)      { ia = face_vtx(pfaces, f, 0, is64, kVP); ib = face_vtx(pfaces, f, 1, is64, kVP); }
    else if (k == 1) { ia = face_vtx(pfaces, f, 1, is64, kVP); ib = face_vtx(pfaces, f, 2, is64, kVP); }
    else             { ia = face_vtx(pfaces, f, 2, is64, kVP); ib = face_vtx(pfaces, f, 0, is64, kVP); }
    const float* vb = pverts + (size_t)b * kVP * 3;
    float dx = vb[ib*3+0] - vb[ia*3+0];
    float dy = vb[ib*3+1] - vb[ia*3+1];
    float dz = vb[ib*3+2] - vb[ia*3+2];
    se += dx*dx + dy*dy + dz*dz;
  }
  __shared__ float r1a[256], r2a[256], r3a[256], r4a[256];
  r1a[tid] = s1; r2a[tid] = s2; r3a[tid] = sc; r4a[tid] = se;
  __syncthreads();
  for (int off = 128; off > 0; off >>= 1) {
    if (tid < off) {
      r1a[tid] += r1a[tid+off];
      r2a[tid] += r2a[tid+off];
      r3a[tid] += r3a[tid+off];
      r4a[tid] += r4a[tid+off];
    }
    __syncthreads();
  }
  if (tid == 0) {
    const float invN = 1.0f / (float)(kB * kNS);
    float chamfer = r1a[0] * invN + r2a[0] * invN;
    float nloss = 1.0f - r3a[0] * invN;
    float eloss = r4a[0] / (float)(kB * kFP * 3);
    out[0] = 1.0f * chamfer + 0.1f * nloss + 0.5f * eloss;
  }
}

// ---------------- host side ----------------
extern "C" void kernel_launch(void* const* d_in, const int* in_sizes, int n_in,
                              void* d_out, int out_size, void* d_ws, size_t ws_size,
                              hipStream_t stream) {
  const float* pverts = (const float*)d_in[0];
  const int*   pfaces = (const int*)d_in[1];
  const float* gverts = (const float*)d_in[2];
  const int*   gfaces = (const int*)d_in[3];
  float* out = (float*)d_out;

  // ---- workspace budget check (diagnostic: out=-1 if too small) ----
  const size_t needF =
      (size_t)kB*kFP + (size_t)kB*kFG +          // inv_a p/g
      (size_t)kB*kFP*3 + (size_t)kB*kFG*3 +      // fnrm p/g
      4*(size_t)kB*kNS*3 +                       // pts p/g, nrm p/g
      2*(size_t)kB*kNS +                         // min p2g/g2p
      3*(size_t)kB*kNS;                          // fidx p/g, idx_p2g (ints)
  if (ws_size < needF * 4) {
    mlk_write_scalar<<<1, 64, 0, stream>>>(out, -1.0f);
    return;
  }

  // --- JAX threefry key chain (host, pure arithmetic) ---
  // key(42) = (0,42); split -> counts iota(4), pairs (0,2),(1,3);
  // rows: kp=(a0,b0), kg=(a1,b1)
  uint32_t a0 = 0u, a1 = 2u; tf2x32(0u, 42u, a0, a1);
  uint32_t b0 = 1u, b1 = 3u; tf2x32(0u, 42u, b0, b1);
  uint32_t kp0 = a0, kp1 = b0;
  uint32_t kg0 = a1, kg1 = b1;
  // split(key,3): counts iota(6); pairs (0,3),(1,4),(2,5);
  // rows: k_face=(P0,Q0) k_u=(R0,P1) k_v=(Q1,R1)
  uint32_t kpred[6], kgt[6];
  {
    uint32_t p0 = 0u, p1 = 3u; tf2x32(kp0, kp1, p0, p1);
    uint32_t q0 = 1u, q1 = 4u; tf2x32(kp0, kp1, q0, q1);
    uint32_t r0 = 2u, r1 = 5u; tf2x32(kp0, kp1, r0, r1);
    kpred[0]=p0; kpred[1]=q0; kpred[2]=r0; kpred[3]=p1; kpred[4]=q1; kpred[5]=r1;
  }
  {
    uint32_t p0 = 0u, p1 = 3u; tf2x32(kg0, kg1, p0, p1);
    uint32_t q0 = 1u, q1 = 4u; tf2x32(kg0, kg1, q0, q1);
    uint32_t r0 = 2u, r1 = 5u; tf2x32(kg0, kg1, r0, r1);
    kgt[0]=p0; kgt[1]=q0; kgt[2]=r0; kgt[3]=p1; kgt[4]=q1; kgt[5]=r1;
  }

  // --- workspace carve (all 4-byte elements) ---
  float* ws = (float*)d_ws;
  float* inv_a_p  = ws; ws += kB * kFP;
  float* inv_a_g  = ws; ws += kB * kFG;
  float* fnrm_p   = ws; ws += kB * kFP * 3;
  float* fnrm_g   = ws; ws += kB * kFG * 3;
  float* pred_pts = ws; ws += kB * kNS * 3;
  float* gt_pts   = ws; ws += kB * kNS * 3;
  float* pred_nrm = ws; ws += kB * kNS * 3;
  float* gt_nrm   = ws; ws += kB * kNS * 3;
  float* min_p2g  = ws; ws += kB * kNS;
  float* min_g2p  = ws; ws += kB * kNS;
  int* fidx_p  = (int*)ws; ws += kB * kNS;
  int* fidx_g  = (int*)ws; ws += kB * kNS;
  int* idx_p2g = (int*)ws; ws += kB * kNS;

  mlk_prep_faces<<<(kB*kFP + 255)/256, 256, 0, stream>>>(pverts, pfaces, kVP, kFP, inv_a_p, fnrm_p);
  mlk_prep_faces<<<(kB*kFG + 255)/256, 256, 0, stream>>>(gverts, gfaces, kVG, kFG, inv_a_g, fnrm_g);

  mlk_cat_sample<<<8192, 256, 0, stream>>>(inv_a_p, kFP, kpred[0], kpred[1], fidx_p);
  mlk_cat_sample<<<8192, 256, 0, stream>>>(inv_a_g, kFG, kgt[0],  kgt[1],  fidx_g);

  mlk_gen_points<<<32, 256, 0, stream>>>(pverts, pfaces, fnrm_p, fidx_p, kVP, kFP,
                                         kpred[2], kpred[3], kpred[4], kpred[5],
                                         pred_pts, pred_nrm);
  mlk_gen_points<<<32, 256, 0, stream>>>(gverts, gfaces, fnrm_g, fidx_g, kVG, kFG,
                                         kgt[2], kgt[3], kgt[4], kgt[5],
                                         gt_pts, gt_nrm);

  mlk_chamfer<<<64, 256, 0, stream>>>(pred_pts, gt_pts, min_p2g, idx_p2g);
  mlk_chamfer<<<64, 256, 0, stream>>>(gt_pts, pred_pts, min_g2p, (int*)nullptr);

  mlk_reduce_loss<<<1, 256, 0, stream>>>(min_p2g, min_g2p, pred_nrm, gt_nrm, idx_p2g,
                                         pverts, pfaces, out);
}

// Round 4
// 684.773 us; speedup vs baseline: 1.3600x; 1.3600x over previous
//
#include <hip/hip_runtime.h>
#include <stdint.h>

constexpr int   kB  = 4;
constexpr int   kNS = 4096;
constexpr int   kVP = 2562;
constexpr int   kFP = 5120;
constexpr int   kVG = 6890;
constexpr int   kFG = 13776;
constexpr float kEPS  = 1e-12f;
constexpr float kTINY = 1.17549435e-38f;

// ---------------- Threefry-2x32 (exact JAX semantics) ----------------
__host__ __device__ inline void tf2x32(uint32_t k0, uint32_t k1,
                                       uint32_t& x0r, uint32_t& x1r) {
  uint32_t ks2 = k0 ^ k1 ^ 0x1BD11BDAu;
  uint32_t x0 = x0r + k0, x1 = x1r + k1;
#define TF_R(r) { x0 += x1; x1 = (x1 << (r)) | (x1 >> (32 - (r))); x1 ^= x0; }
  TF_R(13) TF_R(15) TF_R(26) TF_R(6)
  x0 += k1;  x1 += ks2 + 1u;
  TF_R(17) TF_R(29) TF_R(16) TF_R(24)
  x0 += ks2; x1 += k0 + 2u;
  TF_R(13) TF_R(15) TF_R(26) TF_R(6)
  x0 += k0;  x1 += k1 + 3u;
  TF_R(17) TF_R(29) TF_R(16) TF_R(24)
  x0 += k1;  x1 += ks2 + 4u;
  TF_R(13) TF_R(15) TF_R(26) TF_R(6)
  x0 += ks2; x1 += k0 + 5u;
#undef TF_R
  x0r = x0; x1r = x1;
}

__device__ inline float bits_to_unit(uint32_t b) {
  // JAX: bitcast((b>>9)|0x3f800000) - 1.0  ->  [0,1)
  return __uint_as_float((b >> 9) | 0x3f800000u) - 1.0f;
}

// faces may arrive as int32 (documented) or int64 (reference dtype). For
// int64 little-endian with values < 2^31, every odd 32-bit word is 0.
__device__ inline int faces_is64(const int* __restrict__ faces) {
  return (faces[1] == 0 && faces[3] == 0 && faces[5] == 0 && faces[7] == 0) ? 1 : 0;
}
__device__ inline int face_vtx(const int* __restrict__ faces, int f, int c,
                               int is64, int V) {
  int e = f * 3 + c;
  int v = faces[is64 ? (e << 1) : e];
  return v < 0 ? 0 : (v >= V ? V - 1 : v);
}

// ---------------- trivial diagnostic kernel ----------------
__global__ void mlk_write_scalar(float* out, float val) {
  if (threadIdx.x == 0 && blockIdx.x == 0) out[0] = val;
}

// ---------------- face geometry: 1/(area+eps) and normals ----------------
__global__ __launch_bounds__(256) void mlk_prep_faces(
    const float* __restrict__ verts, const int* __restrict__ faces,
    int V, int F, float* __restrict__ inv_a, float* __restrict__ fnrm) {
  int idx = blockIdx.x * 256 + threadIdx.x;
  if (idx >= kB * F) return;
  int is64 = faces_is64(faces);
  int b = idx / F, f = idx - b * F;
  int i0 = face_vtx(faces, f, 0, is64, V);
  int i1 = face_vtx(faces, f, 1, is64, V);
  int i2 = face_vtx(faces, f, 2, is64, V);
  const float* vb = verts + (size_t)b * V * 3;
  float ax = vb[i0*3+0], ay = vb[i0*3+1], az = vb[i0*3+2];
  float bx = vb[i1*3+0], by = vb[i1*3+1], bz = vb[i1*3+2];
  float cx = vb[i2*3+0], cy = vb[i2*3+1], cz = vb[i2*3+2];
  float e1x = bx-ax, e1y = by-ay, e1z = bz-az;
  float e2x = cx-ax, e2y = cy-ay, e2z = cz-az;
  float nx = e1y*e2z - e1z*e2y;
  float ny = e1z*e2x - e1x*e2z;
  float nz = e1x*e2y - e1y*e2x;
  float area2 = sqrtf(nx*nx + ny*ny + nz*nz);   // 2*area
  inv_a[idx] = 1.0f / (0.5f*area2 + kEPS);
  float inv_n = 1.0f / (area2 + kEPS);
  fnrm[3*idx+0] = nx*inv_n;
  fnrm[3*idx+1] = ny*inv_n;
  fnrm[3*idx+2] = nz*inv_n;
}

// ---------------- categorical sampling (Gumbel argmax, exact bits) ----------------
// One block handles sample-rows w and w+8192 (threefry pair).
// argmax_f(gumbel + log a) == argmin_f((-log2 u) * inv_a), first-index ties.
__global__ __launch_bounds__(256) void mlk_cat_sample(
    const float* __restrict__ inv_a, int F,
    uint32_t kf0, uint32_t kf1, int* __restrict__ face_idx) {
  int w = blockIdx.x;            // 0..8191
  int tid = threadIdx.x;
  int b1 = w >> 12;              // w / kNS
  int s  = w & (kNS - 1);
  int b2 = b1 + 2;
  const float* p1 = inv_a + b1 * F + tid;
  const float* p2 = inv_a + b2 * F + tid;
  uint32_t base0 = (uint32_t)w * (uint32_t)F;
  uint32_t basep = (uint32_t)(w + 8192) * (uint32_t)F;
  float best0 = INFINITY, best1 = INFINITY;
  int bi0 = 0, bi1 = 0;
#pragma unroll 2
  for (int f = tid; f < F; f += 256, p1 += 256, p2 += 256) {
    uint32_t x0 = base0 + (uint32_t)f;
    uint32_t x1 = basep + (uint32_t)f;
    tf2x32(kf0, kf1, x0, x1);
    float u0 = fmaxf(bits_to_unit(x0), kTINY);
    float u1 = fmaxf(bits_to_unit(x1), kTINY);
    float s0 = -__log2f(u0) * (*p1);
    float s1 = -__log2f(u1) * (*p2);
    if (s0 < best0) { best0 = s0; bi0 = f; }
    if (s1 < best1) { best1 = s1; bi1 = f; }
  }
  __shared__ float sv0[256], sv1[256];
  __shared__ int   si0[256], si1[256];
  sv0[tid] = best0; si0[tid] = bi0;
  sv1[tid] = best1; si1[tid] = bi1;
  __syncthreads();
  for (int off = 128; off > 0; off >>= 1) {
    if (tid < off) {
      if (sv0[tid+off] < sv0[tid] ||
          (sv0[tid+off] == sv0[tid] && si0[tid+off] < si0[tid])) {
        sv0[tid] = sv0[tid+off]; si0[tid] = si0[tid+off];
      }
      if (sv1[tid+off] < sv1[tid] ||
          (sv1[tid+off] == sv1[tid] && si1[tid+off] < si1[tid])) {
        sv1[tid] = sv1[tid+off]; si1[tid] = si1[tid+off];
      }
    }
    __syncthreads();
  }
  if (tid == 0) {
    face_idx[b1 * kNS + s] = si0[0];
    face_idx[b2 * kNS + s] = si1[0];
  }
}

// ---------------- barycentric point generation ----------------
__global__ __launch_bounds__(256) void mlk_gen_points(
    const float* __restrict__ verts, const int* __restrict__ faces,
    const float* __restrict__ fnrm, const int* __restrict__ face_idx,
    int V, int F,
    uint32_t ku0, uint32_t ku1, uint32_t kv0, uint32_t kv1,
    float* __restrict__ pts, float* __restrict__ pnrm) {
  int t = blockIdx.x * 256 + threadIdx.x;   // 0..8191
  if (t >= 8192) return;
  int is64 = faces_is64(faces);
  uint32_t ux0 = (uint32_t)t, ux1 = (uint32_t)(t + 8192);
  tf2x32(ku0, ku1, ux0, ux1);
  uint32_t vx0 = (uint32_t)t, vx1 = (uint32_t)(t + 8192);
  tf2x32(kv0, kv1, vx0, vx1);
#pragma unroll
  for (int half = 0; half < 2; ++half) {
    int i = t + half * 8192;                    // flat (b*kNS+s)
    float u = bits_to_unit(half ? ux1 : ux0);
    float v = bits_to_unit(half ? vx1 : vx0);
    int b = i >> 12;
    int fid = face_idx[i];
    fid = fid < 0 ? 0 : (fid >= F ? F - 1 : fid);
    const float* vb = verts + (size_t)b * V * 3;
    int i0 = face_vtx(faces, fid, 0, is64, V);
    int i1 = face_vtx(faces, fid, 1, is64, V);
    int i2 = face_vtx(faces, fid, 2, is64, V);
    float r1 = sqrtf(u);
    float w0 = 1.0f - r1, w1 = r1 * (1.0f - v), w2 = r1 * v;
#pragma unroll
    for (int c = 0; c < 3; ++c) {
      pts[i*3+c] = w0 * vb[i0*3+c] + w1 * vb[i1*3+c] + w2 * vb[i2*3+c];
      pnrm[i*3+c] = fnrm[((size_t)b*F + fid)*3 + c];
    }
  }
}

// ---------------- chamfer: both directions fused, wave-split refs ----------------
// grid = 512 blocks: dir(2) x batch(4) x qchunk(64). Block = 256 thr = 4 waves.
// Lane l of wave w owns query (qchunk*64 + l); wave w scans refs [1024w,1024w+1024).
// Cross-wave combine keeps first-index tie-break (chunk index grows with wave).
__global__ __launch_bounds__(256) void mlk_chamfer2(
    const float* __restrict__ pred_pts, const float* __restrict__ gt_pts,
    float* __restrict__ min_p2g, float* __restrict__ min_g2p,
    int* __restrict__ idx_p2g) {
  int bid = blockIdx.x;
  int dir = bid >> 8;            // 0: pred->gt (needs idx), 1: gt->pred
  int r   = bid & 255;
  int b   = r >> 6;
  int qc  = r & 63;
  const float* qpts = dir ? gt_pts   : pred_pts;
  const float* rpts = dir ? pred_pts : gt_pts;
  int wave = threadIdx.x >> 6;
  int lane = threadIdx.x & 63;
  __shared__ float lp[kNS * 3];  // 48 KB
  const float* rb = rpts + (size_t)b * kNS * 3;
  for (int i = threadIdx.x; i < kNS * 3; i += 256) lp[i] = rb[i];
  __syncthreads();
  int q  = qc * 64 + lane;
  int gi = b * kNS + q;
  float px = qpts[gi*3+0], py = qpts[gi*3+1], pz = qpts[gi*3+2];
  float best = INFINITY; int bidx = 0;
  int m0 = wave * 1024;
#pragma unroll 4
  for (int m = m0; m < m0 + 1024; ++m) {
    float dx = px - lp[m*3+0];
    float dy = py - lp[m*3+1];
    float dz = pz - lp[m*3+2];
    float d2 = dx*dx + dy*dy + dz*dz;
    if (d2 < best) { best = d2; bidx = m; }
  }
  __shared__ float cv[4][64];
  __shared__ int   ci[4][64];
  cv[wave][lane] = best; ci[wave][lane] = bidx;
  __syncthreads();
  if (wave == 0) {
    float bv = cv[0][lane]; int bi = ci[0][lane];
#pragma unroll
    for (int wv = 1; wv < 4; ++wv) {
      float v = cv[wv][lane];
      if (v < bv) { bv = v; bi = ci[wv][lane]; }   // strict <: earlier chunk wins ties
    }
    if (dir == 0) { min_p2g[gi] = bv; idx_p2g[gi] = bi; }
    else          { min_g2p[gi] = bv; }
  }
}

// ---------------- finalize: means + normal loss + edge loss ----------------
__global__ __launch_bounds__(256) void mlk_reduce_loss(
    const float* __restrict__ min_p2g, const float* __restrict__ min_g2p,
    const float* __restrict__ pred_nrm, const float* __restrict__ gt_nrm,
    const int* __restrict__ idx_p2g,
    const float* __restrict__ pverts, const int* __restrict__ pfaces,
    float* __restrict__ out) {
  int tid = threadIdx.x;
  int is64 = faces_is64(pfaces);
  float s1 = 0.f, s2 = 0.f, sc = 0.f, se = 0.f;
  for (int i = tid; i < kB * kNS; i += 256) {
    s1 += min_p2g[i];
    s2 += min_g2p[i];
    int b = i >> 12;
    int m = idx_p2g[i];
    m = m < 0 ? 0 : (m >= kNS ? kNS - 1 : m);
    const float* pn = pred_nrm + (size_t)i * 3;
    const float* gn = gt_nrm + ((size_t)b * kNS + m) * 3;
    sc += fabsf(pn[0]*gn[0] + pn[1]*gn[1] + pn[2]*gn[2]);
  }
  for (int e = tid; e < kB * kFP * 3; e += 256) {
    int b = e / (kFP * 3);
    int r = e - b * kFP * 3;
    int f = r / 3, k = r - f * 3;
    int ia, ib;
    if (k == 0)      { ia = face_vtx(pfaces, f, 0, is64, kVP); ib = face_vtx(pfaces, f, 1, is64, kVP); }
    else if (k == 1) { ia = face_vtx(pfaces, f, 1, is64, kVP); ib = face_vtx(pfaces, f, 2, is64, kVP); }
    else             { ia = face_vtx(pfaces, f, 2, is64, kVP); ib = face_vtx(pfaces, f, 0, is64, kVP); }
    const float* vb = pverts + (size_t)b * kVP * 3;
    float dx = vb[ib*3+0] - vb[ia*3+0];
    float dy = vb[ib*3+1] - vb[ia*3+1];
    float dz = vb[ib*3+2] - vb[ia*3+2];
    se += dx*dx + dy*dy + dz*dz;
  }
  __shared__ float r1a[256], r2a[256], r3a[256], r4a[256];
  r1a[tid] = s1; r2a[tid] = s2; r3a[tid] = sc; r4a[tid] = se;
  __syncthreads();
  for (int off = 128; off > 0; off >>= 1) {
    if (tid < off) {
      r1a[tid] += r1a[tid+off];
      r2a[tid] += r2a[tid+off];
      r3a[tid] += r3a[tid+off];
      r4a[tid] += r4a[tid+off];
    }
    __syncthreads();
  }
  if (tid == 0) {
    const float invN = 1.0f / (float)(kB * kNS);
    float chamfer = r1a[0] * invN + r2a[0] * invN;
    float nloss = 1.0f - r3a[0] * invN;
    float eloss = r4a[0] / (float)(kB * kFP * 3);
    out[0] = 1.0f * chamfer + 0.1f * nloss + 0.5f * eloss;
  }
}

// ---------------- host side ----------------
extern "C" void kernel_launch(void* const* d_in, const int* in_sizes, int n_in,
                              void* d_out, int out_size, void* d_ws, size_t ws_size,
                              hipStream_t stream) {
  const float* pverts = (const float*)d_in[0];
  const int*   pfaces = (const int*)d_in[1];
  const float* gverts = (const float*)d_in[2];
  const int*   gfaces = (const int*)d_in[3];
  float* out = (float*)d_out;

  const size_t needF =
      (size_t)kB*kFP + (size_t)kB*kFG +
      (size_t)kB*kFP*3 + (size_t)kB*kFG*3 +
      4*(size_t)kB*kNS*3 +
      2*(size_t)kB*kNS +
      3*(size_t)kB*kNS;
  if (ws_size < needF * 4) {
    mlk_write_scalar<<<1, 64, 0, stream>>>(out, -1.0f);
    return;
  }

  // --- JAX threefry key chain (host, pure arithmetic) ---
  uint32_t a0 = 0u, a1 = 2u; tf2x32(0u, 42u, a0, a1);
  uint32_t b0 = 1u, b1 = 3u; tf2x32(0u, 42u, b0, b1);
  uint32_t kp0 = a0, kp1 = b0;
  uint32_t kg0 = a1, kg1 = b1;
  uint32_t kpred[6], kgt[6];
  {
    uint32_t p0 = 0u, p1 = 3u; tf2x32(kp0, kp1, p0, p1);
    uint32_t q0 = 1u, q1 = 4u; tf2x32(kp0, kp1, q0, q1);
    uint32_t r0 = 2u, r1 = 5u; tf2x32(kp0, kp1, r0, r1);
    kpred[0]=p0; kpred[1]=q0; kpred[2]=r0; kpred[3]=p1; kpred[4]=q1; kpred[5]=r1;
  }
  {
    uint32_t p0 = 0u, p1 = 3u; tf2x32(kg0, kg1, p0, p1);
    uint32_t q0 = 1u, q1 = 4u; tf2x32(kg0, kg1, q0, q1);
    uint32_t r0 = 2u, r1 = 5u; tf2x32(kg0, kg1, r0, r1);
    kgt[0]=p0; kgt[1]=q0; kgt[2]=r0; kgt[3]=p1; kgt[4]=q1; kgt[5]=r1;
  }

  // --- workspace carve (all 4-byte elements) ---
  float* ws = (float*)d_ws;
  float* inv_a_p  = ws; ws += kB * kFP;
  float* inv_a_g  = ws; ws += kB * kFG;
  float* fnrm_p   = ws; ws += kB * kFP * 3;
  float* fnrm_g   = ws; ws += kB * kFG * 3;
  float* pred_pts = ws; ws += kB * kNS * 3;
  float* gt_pts   = ws; ws += kB * kNS * 3;
  float* pred_nrm = ws; ws += kB * kNS * 3;
  float* gt_nrm   = ws; ws += kB * kNS * 3;
  float* min_p2g  = ws; ws += kB * kNS;
  float* min_g2p  = ws; ws += kB * kNS;
  int* fidx_p  = (int*)ws; ws += kB * kNS;
  int* fidx_g  = (int*)ws; ws += kB * kNS;
  int* idx_p2g = (int*)ws; ws += kB * kNS;

  mlk_prep_faces<<<(kB*kFP + 255)/256, 256, 0, stream>>>(pverts, pfaces, kVP, kFP, inv_a_p, fnrm_p);
  mlk_prep_faces<<<(kB*kFG + 255)/256, 256, 0, stream>>>(gverts, gfaces, kVG, kFG, inv_a_g, fnrm_g);

  mlk_cat_sample<<<8192, 256, 0, stream>>>(inv_a_p, kFP, kpred[0], kpred[1], fidx_p);
  mlk_cat_sample<<<8192, 256, 0, stream>>>(inv_a_g, kFG, kgt[0],  kgt[1],  fidx_g);

  mlk_gen_points<<<32, 256, 0, stream>>>(pverts, pfaces, fnrm_p, fidx_p, kVP, kFP,
                                         kpred[2], kpred[3], kpred[4], kpred[5],
                                         pred_pts, pred_nrm);
  mlk_gen_points<<<32, 256, 0, stream>>>(gverts, gfaces, fnrm_g, fidx_g, kVG, kFG,
                                         kgt[2], kgt[3], kgt[4], kgt[5],
                                         gt_pts, gt_nrm);

  mlk_chamfer2<<<512, 256, 0, stream>>>(pred_pts, gt_pts, min_p2g, min_g2p, idx_p2g);

  mlk_reduce_loss<<<1, 256, 0, stream>>>(min_p2g, min_g2p, pred_nrm, gt_nrm, idx_p2g,
                                         pverts, pfaces, out);
}

// Round 5
// 305.558 us; speedup vs baseline: 3.0479x; 2.2411x over previous
//
#include <hip/hip_runtime.h>
#include <stdint.h>

constexpr int   kB  = 4;
constexpr int   kNS = 4096;
constexpr int   kVP = 2562;
constexpr int   kFP = 5120;
constexpr int   kVG = 6890;
constexpr int   kFG = 13776;
constexpr float kEPS  = 1e-12f;

// ---------------- Threefry-2x32 (exact JAX semantics; used for u,v and CDF draws) ----------------
__host__ __device__ inline void tf2x32(uint32_t k0, uint32_t k1,
                                       uint32_t& x0r, uint32_t& x1r) {
  uint32_t ks2 = k0 ^ k1 ^ 0x1BD11BDAu;
  uint32_t x0 = x0r + k0, x1 = x1r + k1;
#define TF_R(r) { x0 += x1; x1 = (x1 << (r)) | (x1 >> (32 - (r))); x1 ^= x0; }
  TF_R(13) TF_R(15) TF_R(26) TF_R(6)
  x0 += k1;  x1 += ks2 + 1u;
  TF_R(17) TF_R(29) TF_R(16) TF_R(24)
  x0 += ks2; x1 += k0 + 2u;
  TF_R(13) TF_R(15) TF_R(26) TF_R(6)
  x0 += k0;  x1 += k1 + 3u;
  TF_R(17) TF_R(29) TF_R(16) TF_R(24)
  x0 += k1;  x1 += ks2 + 4u;
  TF_R(13) TF_R(15) TF_R(26) TF_R(6)
  x0 += ks2; x1 += k0 + 5u;
#undef TF_R
  x0r = x0; x1r = x1;
}

__device__ inline float bits_to_unit(uint32_t b) {
  // JAX: bitcast((b>>9)|0x3f800000) - 1.0  ->  [0,1)
  return __uint_as_float((b >> 9) | 0x3f800000u) - 1.0f;
}

// faces may arrive as int32 (documented) or int64 (reference dtype). For
// int64 little-endian with values < 2^31, every odd 32-bit word is 0.
__device__ inline int faces_is64(const int* __restrict__ faces) {
  return (faces[1] == 0 && faces[3] == 0 && faces[5] == 0 && faces[7] == 0) ? 1 : 0;
}
__device__ inline int face_vtx(const int* __restrict__ faces, int f, int c,
                               int is64, int V) {
  int e = f * 3 + c;
  int v = faces[is64 ? (e << 1) : e];
  return v < 0 ? 0 : (v >= V ? V - 1 : v);
}

// ---------------- trivial diagnostic kernel ----------------
__global__ void mlk_write_scalar(float* out, float val) {
  if (threadIdx.x == 0 && blockIdx.x == 0) out[0] = val;
}

// ---------------- face geometry: weight (area+eps) and normals ----------------
__global__ __launch_bounds__(256) void mlk_prep_faces(
    const float* __restrict__ verts, const int* __restrict__ faces,
    int V, int F, float* __restrict__ warea, float* __restrict__ fnrm) {
  int idx = blockIdx.x * 256 + threadIdx.x;
  if (idx >= kB * F) return;
  int is64 = faces_is64(faces);
  int b = idx / F, f = idx - b * F;
  int i0 = face_vtx(faces, f, 0, is64, V);
  int i1 = face_vtx(faces, f, 1, is64, V);
  int i2 = face_vtx(faces, f, 2, is64, V);
  const float* vb = verts + (size_t)b * V * 3;
  float ax = vb[i0*3+0], ay = vb[i0*3+1], az = vb[i0*3+2];
  float bx = vb[i1*3+0], by = vb[i1*3+1], bz = vb[i1*3+2];
  float cx = vb[i2*3+0], cy = vb[i2*3+1], cz = vb[i2*3+2];
  float e1x = bx-ax, e1y = by-ay, e1z = bz-az;
  float e2x = cx-ax, e2y = cy-ay, e2z = cz-az;
  float nx = e1y*e2z - e1z*e2y;
  float ny = e1z*e2x - e1x*e2z;
  float nz = e1x*e2y - e1y*e2x;
  float area2 = sqrtf(nx*nx + ny*ny + nz*nz);   // 2*area
  warea[idx] = 0.5f * area2 + kEPS;             // categorical weight: P(f) ∝ area+eps
  float inv_n = 1.0f / (area2 + kEPS);
  fnrm[3*idx+0] = nx*inv_n;
  fnrm[3*idx+1] = ny*inv_n;
  fnrm[3*idx+2] = nz*inv_n;
}

// ---------------- in-place inclusive prefix sum over weights, per batch ----------------
// grid = kB blocks; block b scans w[b*F .. b*F+F). Chunk-sequential + LDS scan
// of 256 chunk totals; deterministic summation order.
__global__ __launch_bounds__(256) void mlk_prefix(float* __restrict__ w, int F) {
  int b = blockIdx.x, tid = threadIdx.x;
  float* wb = w + (size_t)b * F;
  int C = (F + 255) / 256;
  int lo = tid * C;
  int hi = lo + C; if (hi > F) hi = F; if (lo > F) lo = F;
  float s = 0.f;
  for (int i = lo; i < hi; ++i) s += wb[i];
  __shared__ float ps[256];
  ps[tid] = s;
  __syncthreads();
  for (int off = 1; off < 256; off <<= 1) {
    float v = (tid >= off) ? ps[tid - off] : 0.f;
    __syncthreads();
    ps[tid] += v;
    __syncthreads();
  }
  float p = ps[tid] - s;            // exclusive offset for this chunk
  for (int i = lo; i < hi; ++i) { p += wb[i]; wb[i] = p; }
}

// ---------------- categorical via inverse-CDF (1 uniform + binary search / sample) ----------------
// Thread t draws rows t and t+8192 from one threefry call (JAX-quality bits).
__global__ __launch_bounds__(256) void mlk_cdf_sample(
    const float* __restrict__ pref, int F,
    uint32_t k0, uint32_t k1, int* __restrict__ face_idx) {
  int t = blockIdx.x * 256 + threadIdx.x;   // 0..8191
  if (t >= 8192) return;
  uint32_t x0 = (uint32_t)t, x1 = (uint32_t)(t + 8192);
  tf2x32(k0, k1, x0, x1);
#pragma unroll
  for (int half = 0; half < 2; ++half) {
    int i = t + half * 8192;                // flat (b*kNS+s)
    float u = bits_to_unit(half ? x1 : x0);
    int b = i >> 12;
    const float* Pb = pref + (size_t)b * F;
    float target = u * Pb[F - 1];
    int lo = 0, hi = F - 1;
    while (lo < hi) {                       // first f with P_incl[f] > target
      int mid = (lo + hi) >> 1;
      if (Pb[mid] > target) hi = mid; else lo = mid + 1;
    }
    face_idx[i] = lo;
  }
}

// ---------------- barycentric point generation (threefry u,v unchanged) ----------------
__global__ __launch_bounds__(256) void mlk_gen_points(
    const float* __restrict__ verts, const int* __restrict__ faces,
    const float* __restrict__ fnrm, const int* __restrict__ face_idx,
    int V, int F,
    uint32_t ku0, uint32_t ku1, uint32_t kv0, uint32_t kv1,
    float* __restrict__ pts, float* __restrict__ pnrm) {
  int t = blockIdx.x * 256 + threadIdx.x;   // 0..8191
  if (t >= 8192) return;
  int is64 = faces_is64(faces);
  uint32_t ux0 = (uint32_t)t, ux1 = (uint32_t)(t + 8192);
  tf2x32(ku0, ku1, ux0, ux1);
  uint32_t vx0 = (uint32_t)t, vx1 = (uint32_t)(t + 8192);
  tf2x32(kv0, kv1, vx0, vx1);
#pragma unroll
  for (int half = 0; half < 2; ++half) {
    int i = t + half * 8192;                    // flat (b*kNS+s)
    float u = bits_to_unit(half ? ux1 : ux0);
    float v = bits_to_unit(half ? vx1 : vx0);
    int b = i >> 12;
    int fid = face_idx[i];
    fid = fid < 0 ? 0 : (fid >= F ? F - 1 : fid);
    const float* vb = verts + (size_t)b * V * 3;
    int i0 = face_vtx(faces, fid, 0, is64, V);
    int i1 = face_vtx(faces, fid, 1, is64, V);
    int i2 = face_vtx(faces, fid, 2, is64, V);
    float r1 = sqrtf(u);
    float w0 = 1.0f - r1, w1 = r1 * (1.0f - v), w2 = r1 * v;
#pragma unroll
    for (int c = 0; c < 3; ++c) {
      pts[i*3+c] = w0 * vb[i0*3+c] + w1 * vb[i1*3+c] + w2 * vb[i2*3+c];
      pnrm[i*3+c] = fnrm[((size_t)b*F + fid)*3 + c];
    }
  }
}

// ---------------- chamfer: both directions fused, wave-split refs ----------------
__global__ __launch_bounds__(256) void mlk_chamfer2(
    const float* __restrict__ pred_pts, const float* __restrict__ gt_pts,
    float* __restrict__ min_p2g, float* __restrict__ min_g2p,
    int* __restrict__ idx_p2g) {
  int bid = blockIdx.x;
  int dir = bid >> 8;            // 0: pred->gt (needs idx), 1: gt->pred
  int r   = bid & 255;
  int b   = r >> 6;
  int qc  = r & 63;
  const float* qpts = dir ? gt_pts   : pred_pts;
  const float* rpts = dir ? pred_pts : gt_pts;
  int wave = threadIdx.x >> 6;
  int lane = threadIdx.x & 63;
  __shared__ float lp[kNS * 3];  // 48 KB
  const float* rb = rpts + (size_t)b * kNS * 3;
  for (int i = threadIdx.x; i < kNS * 3; i += 256) lp[i] = rb[i];
  __syncthreads();
  int q  = qc * 64 + lane;
  int gi = b * kNS + q;
  float px = qpts[gi*3+0], py = qpts[gi*3+1], pz = qpts[gi*3+2];
  float best = INFINITY; int bidx = 0;
  int m0 = wave * 1024;
#pragma unroll 4
  for (int m = m0; m < m0 + 1024; ++m) {
    float dx = px - lp[m*3+0];
    float dy = py - lp[m*3+1];
    float dz = pz - lp[m*3+2];
    float d2 = dx*dx + dy*dy + dz*dz;
    if (d2 < best) { best = d2; bidx = m; }
  }
  __shared__ float cv[4][64];
  __shared__ int   ci[4][64];
  cv[wave][lane] = best; ci[wave][lane] = bidx;
  __syncthreads();
  if (wave == 0) {
    float bv = cv[0][lane]; int bi = ci[0][lane];
#pragma unroll
    for (int wv = 1; wv < 4; ++wv) {
      float v = cv[wv][lane];
      if (v < bv) { bv = v; bi = ci[wv][lane]; }
    }
    if (dir == 0) { min_p2g[gi] = bv; idx_p2g[gi] = bi; }
    else          { min_g2p[gi] = bv; }
  }
}

// ---------------- finalize: means + normal loss + edge loss ----------------
__global__ __launch_bounds__(256) void mlk_reduce_loss(
    const float* __restrict__ min_p2g, const float* __restrict__ min_g2p,
    const float* __restrict__ pred_nrm, const float* __restrict__ gt_nrm,
    const int* __restrict__ idx_p2g,
    const float* __restrict__ pverts, const int* __restrict__ pfaces,
    float* __restrict__ out) {
  int tid = threadIdx.x;
  int is64 = faces_is64(pfaces);
  float s1 = 0.f, s2 = 0.f, sc = 0.f, se = 0.f;
  for (int i = tid; i < kB * kNS; i += 256) {
    s1 += min_p2g[i];
    s2 += min_g2p[i];
    int b = i >> 12;
    int m = idx_p2g[i];
    m = m < 0 ? 0 : (m >= kNS ? kNS - 1 : m);
    const float* pn = pred_nrm + (size_t)i * 3;
    const float* gn = gt_nrm + ((size_t)b * kNS + m) * 3;
    sc += fabsf(pn[0]*gn[0] + pn[1]*gn[1] + pn[2]*gn[2]);
  }
  for (int e = tid; e < kB * kFP * 3; e += 256) {
    int b = e / (kFP * 3);
    int r = e - b * kFP * 3;
    int f = r / 3, k = r - f * 3;
    int ia, ib;
    if (k == 0)      { ia = face_vtx(pfaces, f, 0, is64, kVP); ib = face_vtx(pfaces, f, 1, is64, kVP); }
    else if (k == 1) { ia = face_vtx(pfaces, f, 1, is64, kVP); ib = face_vtx(pfaces, f, 2, is64, kVP); }
    else             { ia = face_vtx(pfaces, f, 2, is64, kVP); ib = face_vtx(pfaces, f, 0, is64, kVP); }
    const float* vb = pverts + (size_t)b * kVP * 3;
    float dx = vb[ib*3+0] - vb[ia*3+0];
    float dy = vb[ib*3+1] - vb[ia*3+1];
    float dz = vb[ib*3+2] - vb[ia*3+2];
    se += dx*dx + dy*dy + dz*dz;
  }
  __shared__ float r1a[256], r2a[256], r3a[256], r4a[256];
  r1a[tid] = s1; r2a[tid] = s2; r3a[tid] = sc; r4a[tid] = se;
  __syncthreads();
  for (int off = 128; off > 0; off >>= 1) {
    if (tid < off) {
      r1a[tid] += r1a[tid+off];
      r2a[tid] += r2a[tid+off];
      r3a[tid] += r3a[tid+off];
      r4a[tid] += r4a[tid+off];
    }
    __syncthreads();
  }
  if (tid == 0) {
    const float invN = 1.0f / (float)(kB * kNS);
    float chamfer = r1a[0] * invN + r2a[0] * invN;
    float nloss = 1.0f - r3a[0] * invN;
    float eloss = r4a[0] / (float)(kB * kFP * 3);
    out[0] = 1.0f * chamfer + 0.1f * nloss + 0.5f * eloss;
  }
}

// ---------------- host side ----------------
extern "C" void kernel_launch(void* const* d_in, const int* in_sizes, int n_in,
                              void* d_out, int out_size, void* d_ws, size_t ws_size,
                              hipStream_t stream) {
  const float* pverts = (const float*)d_in[0];
  const int*   pfaces = (const int*)d_in[1];
  const float* gverts = (const float*)d_in[2];
  const int*   gfaces = (const int*)d_in[3];
  float* out = (float*)d_out;

  const size_t needF =
      (size_t)kB*kFP + (size_t)kB*kFG +          // weights -> prefix (in-place)
      (size_t)kB*kFP*3 + (size_t)kB*kFG*3 +
      4*(size_t)kB*kNS*3 +
      2*(size_t)kB*kNS +
      3*(size_t)kB*kNS;
  if (ws_size < needF * 4) {
    mlk_write_scalar<<<1, 64, 0, stream>>>(out, -1.0f);
    return;
  }

  // --- JAX threefry key chain (host, pure arithmetic) ---
  uint32_t a0 = 0u, a1 = 2u; tf2x32(0u, 42u, a0, a1);
  uint32_t b0 = 1u, b1 = 3u; tf2x32(0u, 42u, b0, b1);
  uint32_t kp0 = a0, kp1 = b0;
  uint32_t kg0 = a1, kg1 = b1;
  uint32_t kpred[6], kgt[6];
  {
    uint32_t p0 = 0u, p1 = 3u; tf2x32(kp0, kp1, p0, p1);
    uint32_t q0 = 1u, q1 = 4u; tf2x32(kp0, kp1, q0, q1);
    uint32_t r0 = 2u, r1 = 5u; tf2x32(kp0, kp1, r0, r1);
    kpred[0]=p0; kpred[1]=q0; kpred[2]=r0; kpred[3]=p1; kpred[4]=q1; kpred[5]=r1;
  }
  {
    uint32_t p0 = 0u, p1 = 3u; tf2x32(kg0, kg1, p0, p1);
    uint32_t q0 = 1u, q1 = 4u; tf2x32(kg0, kg1, q0, q1);
    uint32_t r0 = 2u, r1 = 5u; tf2x32(kg0, kg1, r0, r1);
    kgt[0]=p0; kgt[1]=q0; kgt[2]=r0; kgt[3]=p1; kgt[4]=q1; kgt[5]=r1;
  }

  // --- workspace carve (all 4-byte elements) ---
  float* ws = (float*)d_ws;
  float* pref_p   = ws; ws += kB * kFP;          // weights, then in-place prefix
  float* pref_g   = ws; ws += kB * kFG;
  float* fnrm_p   = ws; ws += kB * kFP * 3;
  float* fnrm_g   = ws; ws += kB * kFG * 3;
  float* pred_pts = ws; ws += kB * kNS * 3;
  float* gt_pts   = ws; ws += kB * kNS * 3;
  float* pred_nrm = ws; ws += kB * kNS * 3;
  float* gt_nrm   = ws; ws += kB * kNS * 3;
  float* min_p2g  = ws; ws += kB * kNS;
  float* min_g2p  = ws; ws += kB * kNS;
  int* fidx_p  = (int*)ws; ws += kB * kNS;
  int* fidx_g  = (int*)ws; ws += kB * kNS;
  int* idx_p2g = (int*)ws; ws += kB * kNS;

  mlk_prep_faces<<<(kB*kFP + 255)/256, 256, 0, stream>>>(pverts, pfaces, kVP, kFP, pref_p, fnrm_p);
  mlk_prep_faces<<<(kB*kFG + 255)/256, 256, 0, stream>>>(gverts, gfaces, kVG, kFG, pref_g, fnrm_g);

  mlk_prefix<<<kB, 256, 0, stream>>>(pref_p, kFP);
  mlk_prefix<<<kB, 256, 0, stream>>>(pref_g, kFG);

  mlk_cdf_sample<<<32, 256, 0, stream>>>(pref_p, kFP, kpred[0], kpred[1], fidx_p);
  mlk_cdf_sample<<<32, 256, 0, stream>>>(pref_g, kFG, kgt[0],  kgt[1],  fidx_g);

  mlk_gen_points<<<32, 256, 0, stream>>>(pverts, pfaces, fnrm_p, fidx_p, kVP, kFP,
                                         kpred[2], kpred[3], kpred[4], kpred[5],
                                         pred_pts, pred_nrm);
  mlk_gen_points<<<32, 256, 0, stream>>>(gverts, gfaces, fnrm_g, fidx_g, kVG, kFG,
                                         kgt[2], kgt[3], kgt[4], kgt[5],
                                         gt_pts, gt_nrm);

  mlk_chamfer2<<<512, 256, 0, stream>>>(pred_pts, gt_pts, min_p2g, min_g2p, idx_p2g);

  mlk_reduce_loss<<<1, 256, 0, stream>>>(min_p2g, min_g2p, pred_nrm, gt_nrm, idx_p2g,
                                         pverts, pfaces, out);
}

// Round 6
// 119.391 us; speedup vs baseline: 7.8004x; 2.5593x over previous
//
#include <hip/hip_runtime.h>
#include <stdint.h>

constexpr int   kB  = 4;
constexpr int   kNS = 4096;
constexpr int   kVP = 2562;
constexpr int   kFP = 5120;
constexpr int   kVG = 6890;
constexpr int   kFG = 13776;
constexpr float kEPS  = 1e-12f;
constexpr int   kPB  = 256;   // partial-reduction blocks

// ---------------- Threefry-2x32 (exact JAX semantics; used for u,v and CDF draws) ----------------
__host__ __device__ inline void tf2x32(uint32_t k0, uint32_t k1,
                                       uint32_t& x0r, uint32_t& x1r) {
  uint32_t ks2 = k0 ^ k1 ^ 0x1BD11BDAu;
  uint32_t x0 = x0r + k0, x1 = x1r + k1;
#define TF_R(r) { x0 += x1; x1 = (x1 << (r)) | (x1 >> (32 - (r))); x1 ^= x0; }
  TF_R(13) TF_R(15) TF_R(26) TF_R(6)
  x0 += k1;  x1 += ks2 + 1u;
  TF_R(17) TF_R(29) TF_R(16) TF_R(24)
  x0 += ks2; x1 += k0 + 2u;
  TF_R(13) TF_R(15) TF_R(26) TF_R(6)
  x0 += k0;  x1 += k1 + 3u;
  TF_R(17) TF_R(29) TF_R(16) TF_R(24)
  x0 += k1;  x1 += ks2 + 4u;
  TF_R(13) TF_R(15) TF_R(26) TF_R(6)
  x0 += ks2; x1 += k0 + 5u;
#undef TF_R
  x0r = x0; x1r = x1;
}

__device__ inline float bits_to_unit(uint32_t b) {
  // JAX: bitcast((b>>9)|0x3f800000) - 1.0  ->  [0,1)
  return __uint_as_float((b >> 9) | 0x3f800000u) - 1.0f;
}

// faces may arrive as int32 (documented) or int64 (reference dtype). For
// int64 little-endian with values < 2^31, every odd 32-bit word is 0.
__device__ inline int faces_is64(const int* __restrict__ faces) {
  return (faces[1] == 0 && faces[3] == 0 && faces[5] == 0 && faces[7] == 0) ? 1 : 0;
}
__device__ inline int face_vtx(const int* __restrict__ faces, int f, int c,
                               int is64, int V) {
  int e = f * 3 + c;
  int v = faces[is64 ? (e << 1) : e];
  return v < 0 ? 0 : (v >= V ? V - 1 : v);
}

// ---------------- trivial diagnostic kernel ----------------
__global__ void mlk_write_scalar(float* out, float val) {
  if (threadIdx.x == 0 && blockIdx.x == 0) out[0] = val;
}

// ---------------- face geometry: weight (area+eps) and normals ----------------
__global__ __launch_bounds__(256) void mlk_prep_faces(
    const float* __restrict__ verts, const int* __restrict__ faces,
    int V, int F, float* __restrict__ warea, float* __restrict__ fnrm) {
  int idx = blockIdx.x * 256 + threadIdx.x;
  if (idx >= kB * F) return;
  int is64 = faces_is64(faces);
  int b = idx / F, f = idx - b * F;
  int i0 = face_vtx(faces, f, 0, is64, V);
  int i1 = face_vtx(faces, f, 1, is64, V);
  int i2 = face_vtx(faces, f, 2, is64, V);
  const float* vb = verts + (size_t)b * V * 3;
  float ax = vb[i0*3+0], ay = vb[i0*3+1], az = vb[i0*3+2];
  float bx = vb[i1*3+0], by = vb[i1*3+1], bz = vb[i1*3+2];
  float cx = vb[i2*3+0], cy = vb[i2*3+1], cz = vb[i2*3+2];
  float e1x = bx-ax, e1y = by-ay, e1z = bz-az;
  float e2x = cx-ax, e2y = cy-ay, e2z = cz-az;
  float nx = e1y*e2z - e1z*e2y;
  float ny = e1z*e2x - e1x*e2z;
  float nz = e1x*e2y - e1y*e2x;
  float area2 = sqrtf(nx*nx + ny*ny + nz*nz);   // 2*area
  warea[idx] = 0.5f * area2 + kEPS;             // categorical weight: P(f) ∝ area+eps
  float inv_n = 1.0f / (area2 + kEPS);
  fnrm[3*idx+0] = nx*inv_n;
  fnrm[3*idx+1] = ny*inv_n;
  fnrm[3*idx+2] = nz*inv_n;
}

// ---------------- in-place inclusive prefix sum over weights, per batch ----------------
__global__ __launch_bounds__(256) void mlk_prefix(float* __restrict__ w, int F) {
  int b = blockIdx.x, tid = threadIdx.x;
  float* wb = w + (size_t)b * F;
  int C = (F + 255) / 256;
  int lo = tid * C;
  int hi = lo + C; if (hi > F) hi = F; if (lo > F) lo = F;
  float s = 0.f;
  for (int i = lo; i < hi; ++i) s += wb[i];
  __shared__ float ps[256];
  ps[tid] = s;
  __syncthreads();
  for (int off = 1; off < 256; off <<= 1) {
    float v = (tid >= off) ? ps[tid - off] : 0.f;
    __syncthreads();
    ps[tid] += v;
    __syncthreads();
  }
  float p = ps[tid] - s;            // exclusive offset for this chunk
  for (int i = lo; i < hi; ++i) { p += wb[i]; wb[i] = p; }
}

// ---------------- categorical via inverse-CDF (1 uniform + binary search / sample) ----------------
__global__ __launch_bounds__(256) void mlk_cdf_sample(
    const float* __restrict__ pref, int F,
    uint32_t k0, uint32_t k1, int* __restrict__ face_idx) {
  int t = blockIdx.x * 256 + threadIdx.x;   // 0..8191
  if (t >= 8192) return;
  uint32_t x0 = (uint32_t)t, x1 = (uint32_t)(t + 8192);
  tf2x32(k0, k1, x0, x1);
#pragma unroll
  for (int half = 0; half < 2; ++half) {
    int i = t + half * 8192;                // flat (b*kNS+s)
    float u = bits_to_unit(half ? x1 : x0);
    int b = i >> 12;
    const float* Pb = pref + (size_t)b * F;
    float target = u * Pb[F - 1];
    int lo = 0, hi = F - 1;
    while (lo < hi) {                       // first f with P_incl[f] > target
      int mid = (lo + hi) >> 1;
      if (Pb[mid] > target) hi = mid; else lo = mid + 1;
    }
    face_idx[i] = lo;
  }
}

// ---------------- barycentric point generation (threefry u,v unchanged) ----------------
__global__ __launch_bounds__(256) void mlk_gen_points(
    const float* __restrict__ verts, const int* __restrict__ faces,
    const float* __restrict__ fnrm, const int* __restrict__ face_idx,
    int V, int F,
    uint32_t ku0, uint32_t ku1, uint32_t kv0, uint32_t kv1,
    float* __restrict__ pts, float* __restrict__ pnrm) {
  int t = blockIdx.x * 256 + threadIdx.x;   // 0..8191
  if (t >= 8192) return;
  int is64 = faces_is64(faces);
  uint32_t ux0 = (uint32_t)t, ux1 = (uint32_t)(t + 8192);
  tf2x32(ku0, ku1, ux0, ux1);
  uint32_t vx0 = (uint32_t)t, vx1 = (uint32_t)(t + 8192);
  tf2x32(kv0, kv1, vx0, vx1);
#pragma unroll
  for (int half = 0; half < 2; ++half) {
    int i = t + half * 8192;                    // flat (b*kNS+s)
    float u = bits_to_unit(half ? ux1 : ux0);
    float v = bits_to_unit(half ? vx1 : vx0);
    int b = i >> 12;
    int fid = face_idx[i];
    fid = fid < 0 ? 0 : (fid >= F ? F - 1 : fid);
    const float* vb = verts + (size_t)b * V * 3;
    int i0 = face_vtx(faces, fid, 0, is64, V);
    int i1 = face_vtx(faces, fid, 1, is64, V);
    int i2 = face_vtx(faces, fid, 2, is64, V);
    float r1 = sqrtf(u);
    float w0 = 1.0f - r1, w1 = r1 * (1.0f - v), w2 = r1 * v;
#pragma unroll
    for (int c = 0; c < 3; ++c) {
      pts[i*3+c] = w0 * vb[i0*3+c] + w1 * vb[i1*3+c] + w2 * vb[i2*3+c];
      pnrm[i*3+c] = fnrm[((size_t)b*F + fid)*3 + c];
    }
  }
}

// ---------------- chamfer: both directions fused, wave-split refs ----------------
__global__ __launch_bounds__(256) void mlk_chamfer2(
    const float* __restrict__ pred_pts, const float* __restrict__ gt_pts,
    float* __restrict__ min_p2g, float* __restrict__ min_g2p,
    int* __restrict__ idx_p2g) {
  int bid = blockIdx.x;
  int dir = bid >> 8;            // 0: pred->gt (needs idx), 1: gt->pred
  int r   = bid & 255;
  int b   = r >> 6;
  int qc  = r & 63;
  const float* qpts = dir ? gt_pts   : pred_pts;
  const float* rpts = dir ? pred_pts : gt_pts;
  int wave = threadIdx.x >> 6;
  int lane = threadIdx.x & 63;
  __shared__ float lp[kNS * 3];  // 48 KB
  const float* rb = rpts + (size_t)b * kNS * 3;
  for (int i = threadIdx.x; i < kNS * 3; i += 256) lp[i] = rb[i];
  __syncthreads();
  int q  = qc * 64 + lane;
  int gi = b * kNS + q;
  float px = qpts[gi*3+0], py = qpts[gi*3+1], pz = qpts[gi*3+2];
  float best = INFINITY; int bidx = 0;
  int m0 = wave * 1024;
#pragma unroll 4
  for (int m = m0; m < m0 + 1024; ++m) {
    float dx = px - lp[m*3+0];
    float dy = py - lp[m*3+1];
    float dz = pz - lp[m*3+2];
    float d2 = dx*dx + dy*dy + dz*dz;
    if (d2 < best) { best = d2; bidx = m; }
  }
  __shared__ float cv[4][64];
  __shared__ int   ci[4][64];
  cv[wave][lane] = best; ci[wave][lane] = bidx;
  __syncthreads();
  if (wave == 0) {
    float bv = cv[0][lane]; int bi = ci[0][lane];
#pragma unroll
    for (int wv = 1; wv < 4; ++wv) {
      float v = cv[wv][lane];
      if (v < bv) { bv = v; bi = ci[wv][lane]; }
    }
    if (dir == 0) { min_p2g[gi] = bv; idx_p2g[gi] = bi; }
    else          { min_g2p[gi] = bv; }
  }
}

// ---------------- loss reduction stage 1: grid-wide partials ----------------
// 77824 reduction elements spread one-per-thread across kPB*256 = 65536 threads
// (grid-stride, <=2 iters). Each block writes 4 partial sums. Deterministic.
__global__ __launch_bounds__(256) void mlk_loss_partial(
    const float* __restrict__ min_p2g, const float* __restrict__ min_g2p,
    const float* __restrict__ pred_nrm, const float* __restrict__ gt_nrm,
    const int* __restrict__ idx_p2g,
    const float* __restrict__ pverts, const int* __restrict__ pfaces,
    float* __restrict__ partial) {
  int tid = threadIdx.x;
  int gidx = blockIdx.x * 256 + tid;
  const int stride = kPB * 256;
  int is64 = faces_is64(pfaces);
  float s1 = 0.f, s2 = 0.f, sc = 0.f, se = 0.f;
  for (int i = gidx; i < kB * kNS; i += stride) {
    s1 += min_p2g[i];
    s2 += min_g2p[i];
    int b = i >> 12;
    int m = idx_p2g[i];
    m = m < 0 ? 0 : (m >= kNS ? kNS - 1 : m);
    const float* pn = pred_nrm + (size_t)i * 3;
    const float* gn = gt_nrm + ((size_t)b * kNS + m) * 3;
    sc += fabsf(pn[0]*gn[0] + pn[1]*gn[1] + pn[2]*gn[2]);
  }
  for (int e = gidx; e < kB * kFP * 3; e += stride) {
    int b = e / (kFP * 3);
    int r = e - b * kFP * 3;
    int f = r / 3, k = r - f * 3;
    int ia, ib;
    if (k == 0)      { ia = face_vtx(pfaces, f, 0, is64, kVP); ib = face_vtx(pfaces, f, 1, is64, kVP); }
    else if (k == 1) { ia = face_vtx(pfaces, f, 1, is64, kVP); ib = face_vtx(pfaces, f, 2, is64, kVP); }
    else             { ia = face_vtx(pfaces, f, 2, is64, kVP); ib = face_vtx(pfaces, f, 0, is64, kVP); }
    const float* vb = pverts + (size_t)b * kVP * 3;
    float dx = vb[ib*3+0] - vb[ia*3+0];
    float dy = vb[ib*3+1] - vb[ia*3+1];
    float dz = vb[ib*3+2] - vb[ia*3+2];
    se += dx*dx + dy*dy + dz*dz;
  }
  __shared__ float r1a[256], r2a[256], r3a[256], r4a[256];
  r1a[tid] = s1; r2a[tid] = s2; r3a[tid] = sc; r4a[tid] = se;
  __syncthreads();
  for (int off = 128; off > 0; off >>= 1) {
    if (tid < off) {
      r1a[tid] += r1a[tid+off];
      r2a[tid] += r2a[tid+off];
      r3a[tid] += r3a[tid+off];
      r4a[tid] += r4a[tid+off];
    }
    __syncthreads();
  }
  if (tid == 0) {
    partial[blockIdx.x*4+0] = r1a[0];
    partial[blockIdx.x*4+1] = r2a[0];
    partial[blockIdx.x*4+2] = r3a[0];
    partial[blockIdx.x*4+3] = r4a[0];
  }
}

// ---------------- loss reduction stage 2: combine kPB partials ----------------
__global__ __launch_bounds__(256) void mlk_loss_combine(
    const float* __restrict__ partial, float* __restrict__ out) {
  int tid = threadIdx.x;
  __shared__ float r1a[256], r2a[256], r3a[256], r4a[256];
  r1a[tid] = partial[tid*4+0];
  r2a[tid] = partial[tid*4+1];
  r3a[tid] = partial[tid*4+2];
  r4a[tid] = partial[tid*4+3];
  __syncthreads();
  for (int off = 128; off > 0; off >>= 1) {
    if (tid < off) {
      r1a[tid] += r1a[tid+off];
      r2a[tid] += r2a[tid+off];
      r3a[tid] += r3a[tid+off];
      r4a[tid] += r4a[tid+off];
    }
    __syncthreads();
  }
  if (tid == 0) {
    const float invN = 1.0f / (float)(kB * kNS);
    float chamfer = r1a[0] * invN + r2a[0] * invN;
    float nloss = 1.0f - r3a[0] * invN;
    float eloss = r4a[0] / (float)(kB * kFP * 3);
    out[0] = 1.0f * chamfer + 0.1f * nloss + 0.5f * eloss;
  }
}

// ---------------- host side ----------------
extern "C" void kernel_launch(void* const* d_in, const int* in_sizes, int n_in,
                              void* d_out, int out_size, void* d_ws, size_t ws_size,
                              hipStream_t stream) {
  const float* pverts = (const float*)d_in[0];
  const int*   pfaces = (const int*)d_in[1];
  const float* gverts = (const float*)d_in[2];
  const int*   gfaces = (const int*)d_in[3];
  float* out = (float*)d_out;

  const size_t needF =
      (size_t)kB*kFP + (size_t)kB*kFG +          // weights -> prefix (in-place)
      (size_t)kB*kFP*3 + (size_t)kB*kFG*3 +
      4*(size_t)kB*kNS*3 +
      2*(size_t)kB*kNS +
      3*(size_t)kB*kNS +
      (size_t)kPB*4;                             // loss partials
  if (ws_size < needF * 4) {
    mlk_write_scalar<<<1, 64, 0, stream>>>(out, -1.0f);
    return;
  }

  // --- JAX threefry key chain (host, pure arithmetic) ---
  uint32_t a0 = 0u, a1 = 2u; tf2x32(0u, 42u, a0, a1);
  uint32_t b0 = 1u, b1 = 3u; tf2x32(0u, 42u, b0, b1);
  uint32_t kp0 = a0, kp1 = b0;
  uint32_t kg0 = a1, kg1 = b1;
  uint32_t kpred[6], kgt[6];
  {
    uint32_t p0 = 0u, p1 = 3u; tf2x32(kp0, kp1, p0, p1);
    uint32_t q0 = 1u, q1 = 4u; tf2x32(kp0, kp1, q0, q1);
    uint32_t r0 = 2u, r1 = 5u; tf2x32(kp0, kp1, r0, r1);
    kpred[0]=p0; kpred[1]=q0; kpred[2]=r0; kpred[3]=p1; kpred[4]=q1; kpred[5]=r1;
  }
  {
    uint32_t p0 = 0u, p1 = 3u; tf2x32(kg0, kg1, p0, p1);
    uint32_t q0 = 1u, q1 = 4u; tf2x32(kg0, kg1, q0, q1);
    uint32_t r0 = 2u, r1 = 5u; tf2x32(kg0, kg1, r0, r1);
    kgt[0]=p0; kgt[1]=q0; kgt[2]=r0; kgt[3]=p1; kgt[4]=q1; kgt[5]=r1;
  }

  // --- workspace carve (all 4-byte elements) ---
  float* ws = (float*)d_ws;
  float* pref_p   = ws; ws += kB * kFP;          // weights, then in-place prefix
  float* pref_g   = ws; ws += kB * kFG;
  float* fnrm_p   = ws; ws += kB * kFP * 3;
  float* fnrm_g   = ws; ws += kB * kFG * 3;
  float* pred_pts = ws; ws += kB * kNS * 3;
  float* gt_pts   = ws; ws += kB * kNS * 3;
  float* pred_nrm = ws; ws += kB * kNS * 3;
  float* gt_nrm   = ws; ws += kB * kNS * 3;
  float* min_p2g  = ws; ws += kB * kNS;
  float* min_g2p  = ws; ws += kB * kNS;
  float* partial  = ws; ws += kPB * 4;
  int* fidx_p  = (int*)ws; ws += kB * kNS;
  int* fidx_g  = (int*)ws; ws += kB * kNS;
  int* idx_p2g = (int*)ws; ws += kB * kNS;

  mlk_prep_faces<<<(kB*kFP + 255)/256, 256, 0, stream>>>(pverts, pfaces, kVP, kFP, pref_p, fnrm_p);
  mlk_prep_faces<<<(kB*kFG + 255)/256, 256, 0, stream>>>(gverts, gfaces, kVG, kFG, pref_g, fnrm_g);

  mlk_prefix<<<kB, 256, 0, stream>>>(pref_p, kFP);
  mlk_prefix<<<kB, 256, 0, stream>>>(pref_g, kFG);

  mlk_cdf_sample<<<32, 256, 0, stream>>>(pref_p, kFP, kpred[0], kpred[1], fidx_p);
  mlk_cdf_sample<<<32, 256, 0, stream>>>(pref_g, kFG, kgt[0],  kgt[1],  fidx_g);

  mlk_gen_points<<<32, 256, 0, stream>>>(pverts, pfaces, fnrm_p, fidx_p, kVP, kFP,
                                         kpred[2], kpred[3], kpred[4], kpred[5],
                                         pred_pts, pred_nrm);
  mlk_gen_points<<<32, 256, 0, stream>>>(gverts, gfaces, fnrm_g, fidx_g, kVG, kFG,
                                         kgt[2], kgt[3], kgt[4], kgt[5],
                                         gt_pts, gt_nrm);

  mlk_chamfer2<<<512, 256, 0, stream>>>(pred_pts, gt_pts, min_p2g, min_g2p, idx_p2g);

  mlk_loss_partial<<<kPB, 256, 0, stream>>>(min_p2g, min_g2p, pred_nrm, gt_nrm, idx_p2g,
                                            pverts, pfaces, partial);
  mlk_loss_combine<<<1, 256, 0, stream>>>(partial, out);
}

// Round 7
// 81.116 us; speedup vs baseline: 11.4811x; 1.4719x over previous
//
#include <hip/hip_runtime.h>
#include <stdint.h>

constexpr int   kB  = 4;
constexpr int   kNS = 4096;
constexpr int   kVP = 2562;
constexpr int   kFP = 5120;
constexpr int   kVG = 6890;
constexpr int   kFG = 13776;
constexpr float kEPS  = 1e-12f;
constexpr int   kPB  = 256;   // partial-reduction blocks
constexpr int   kPREP_P = (kB * kFP + 255) / 256;   // 80
constexpr int   kPREP_G = (kB * kFG + 255) / 256;   // 216

// ---------------- Threefry-2x32 (exact JAX semantics) ----------------
__host__ __device__ inline void tf2x32(uint32_t k0, uint32_t k1,
                                       uint32_t& x0r, uint32_t& x1r) {
  uint32_t ks2 = k0 ^ k1 ^ 0x1BD11BDAu;
  uint32_t x0 = x0r + k0, x1 = x1r + k1;
#define TF_R(r) { x0 += x1; x1 = (x1 << (r)) | (x1 >> (32 - (r))); x1 ^= x0; }
  TF_R(13) TF_R(15) TF_R(26) TF_R(6)
  x0 += k1;  x1 += ks2 + 1u;
  TF_R(17) TF_R(29) TF_R(16) TF_R(24)
  x0 += ks2; x1 += k0 + 2u;
  TF_R(13) TF_R(15) TF_R(26) TF_R(6)
  x0 += k0;  x1 += k1 + 3u;
  TF_R(17) TF_R(29) TF_R(16) TF_R(24)
  x0 += k1;  x1 += ks2 + 4u;
  TF_R(13) TF_R(15) TF_R(26) TF_R(6)
  x0 += ks2; x1 += k0 + 5u;
#undef TF_R
  x0r = x0; x1r = x1;
}

__device__ inline float bits_to_unit(uint32_t b) {
  // JAX: bitcast((b>>9)|0x3f800000) - 1.0  ->  [0,1)
  return __uint_as_float((b >> 9) | 0x3f800000u) - 1.0f;
}

// faces may arrive as int32 (documented) or int64 (reference dtype). For
// int64 little-endian with values < 2^31, every odd 32-bit word is 0.
__device__ inline int faces_is64(const int* __restrict__ faces) {
  return (faces[1] == 0 && faces[3] == 0 && faces[5] == 0 && faces[7] == 0) ? 1 : 0;
}
__device__ inline int face_vtx(const int* __restrict__ faces, int f, int c,
                               int is64, int V) {
  int e = f * 3 + c;
  int v = faces[is64 ? (e << 1) : e];
  return v < 0 ? 0 : (v >= V ? V - 1 : v);
}

// ---------------- trivial diagnostic kernel ----------------
__global__ void mlk_write_scalar(float* out, float val) {
  if (threadIdx.x == 0 && blockIdx.x == 0) out[0] = val;
}

// ---------------- fused face geometry for BOTH meshes ----------------
__global__ __launch_bounds__(256) void mlk_prep_faces2(
    const float* __restrict__ pverts, const int* __restrict__ pfaces,
    const float* __restrict__ gverts, const int* __restrict__ gfaces,
    float* __restrict__ wp, float* __restrict__ np,
    float* __restrict__ wg, float* __restrict__ ng) {
  int which = blockIdx.x >= kPREP_P;
  int blk   = which ? blockIdx.x - kPREP_P : blockIdx.x;
  const float* verts = which ? gverts : pverts;
  const int*   faces = which ? gfaces : pfaces;
  float* warea = which ? wg : wp;
  float* fnrm  = which ? ng : np;
  int V = which ? kVG : kVP;
  int F = which ? kFG : kFP;
  int idx = blk * 256 + threadIdx.x;
  if (idx >= kB * F) return;
  int is64 = faces_is64(faces);
  int b = idx / F, f = idx - b * F;
  int i0 = face_vtx(faces, f, 0, is64, V);
  int i1 = face_vtx(faces, f, 1, is64, V);
  int i2 = face_vtx(faces, f, 2, is64, V);
  const float* vb = verts + (size_t)b * V * 3;
  float ax = vb[i0*3+0], ay = vb[i0*3+1], az = vb[i0*3+2];
  float bx = vb[i1*3+0], by = vb[i1*3+1], bz = vb[i1*3+2];
  float cx = vb[i2*3+0], cy = vb[i2*3+1], cz = vb[i2*3+2];
  float e1x = bx-ax, e1y = by-ay, e1z = bz-az;
  float e2x = cx-ax, e2y = cy-ay, e2z = cz-az;
  float nx = e1y*e2z - e1z*e2y;
  float ny = e1z*e2x - e1x*e2z;
  float nz = e1x*e2y - e1y*e2x;
  float area2 = sqrtf(nx*nx + ny*ny + nz*nz);   // 2*area
  warea[idx] = 0.5f * area2 + kEPS;             // categorical weight
  float inv_n = 1.0f / (area2 + kEPS);
  fnrm[3*idx+0] = nx*inv_n;
  fnrm[3*idx+1] = ny*inv_n;
  fnrm[3*idx+2] = nz*inv_n;
}

// ---------------- fused in-place prefix sums (8 blocks: 4 pred + 4 gt) --------
__global__ __launch_bounds__(256) void mlk_prefix2(
    float* __restrict__ wp, float* __restrict__ wg) {
  int which = blockIdx.x >> 2;
  int b = blockIdx.x & 3, tid = threadIdx.x;
  int F = which ? kFG : kFP;
  float* wb = (which ? wg : wp) + (size_t)b * F;
  int C = (F + 255) / 256;
  int lo = tid * C;
  int hi = lo + C; if (hi > F) hi = F; if (lo > F) lo = F;
  float s = 0.f;
  for (int i = lo; i < hi; ++i) s += wb[i];
  __shared__ float ps[256];
  ps[tid] = s;
  __syncthreads();
  for (int off = 1; off < 256; off <<= 1) {
    float v = (tid >= off) ? ps[tid - off] : 0.f;
    __syncthreads();
    ps[tid] += v;
    __syncthreads();
  }
  float p = ps[tid] - s;            // exclusive offset for this chunk
  for (int i = lo; i < hi; ++i) { p += wb[i]; wb[i] = p; }
}

// ---------------- fused categorical (inverse-CDF) + barycentric gen ----------
// grid 64: blocks 0..31 pred, 32..63 gt. Thread t handles rows t and t+8192.
__global__ __launch_bounds__(256) void mlk_sample_gen(
    const float* __restrict__ pverts, const int* __restrict__ pfaces,
    const float* __restrict__ pref_p, const float* __restrict__ fnrm_p,
    float* __restrict__ pred_pts, float* __restrict__ pred_nrm,
    const float* __restrict__ gverts, const int* __restrict__ gfaces,
    const float* __restrict__ pref_g, const float* __restrict__ fnrm_g,
    float* __restrict__ gt_pts, float* __restrict__ gt_nrm,
    uint32_t pf0, uint32_t pf1, uint32_t pu0, uint32_t pu1, uint32_t pv0, uint32_t pv1,
    uint32_t gf0, uint32_t gf1, uint32_t gu0, uint32_t gu1, uint32_t gv0, uint32_t gv1) {
  int which = blockIdx.x >> 5;
  int t = ((blockIdx.x & 31) << 8) + threadIdx.x;   // 0..8191
  const float* verts = which ? gverts : pverts;
  const int*   faces = which ? gfaces : pfaces;
  const float* pref  = which ? pref_g : pref_p;
  const float* fnrm  = which ? fnrm_g : fnrm_p;
  float* pts  = which ? gt_pts : pred_pts;
  float* pnrm = which ? gt_nrm : pred_nrm;
  int V = which ? kVG : kVP;
  int F = which ? kFG : kFP;
  uint32_t kf0 = which ? gf0 : pf0, kf1 = which ? gf1 : pf1;
  uint32_t ku0 = which ? gu0 : pu0, ku1 = which ? gu1 : pu1;
  uint32_t kv0 = which ? gv0 : pv0, kv1 = which ? gv1 : pv1;
  int is64 = faces_is64(faces);

  uint32_t fx0 = (uint32_t)t, fx1 = (uint32_t)(t + 8192);
  tf2x32(kf0, kf1, fx0, fx1);
  uint32_t ux0 = (uint32_t)t, ux1 = (uint32_t)(t + 8192);
  tf2x32(ku0, ku1, ux0, ux1);
  uint32_t vx0 = (uint32_t)t, vx1 = (uint32_t)(t + 8192);
  tf2x32(kv0, kv1, vx0, vx1);

#pragma unroll
  for (int half = 0; half < 2; ++half) {
    int i = t + half * 8192;                    // flat (b*kNS+s)
    int b = i >> 12;
    // --- inverse-CDF face draw ---
    float uf = bits_to_unit(half ? fx1 : fx0);
    const float* Pb = pref + (size_t)b * F;
    float target = uf * Pb[F - 1];
    int lo = 0, hi = F - 1;
    while (lo < hi) {                           // first f with P_incl[f] > target
      int mid = (lo + hi) >> 1;
      if (Pb[mid] > target) hi = mid; else lo = mid + 1;
    }
    int fid = lo;
    // --- barycentric point ---
    float u = bits_to_unit(half ? ux1 : ux0);
    float v = bits_to_unit(half ? vx1 : vx0);
    const float* vb = verts + (size_t)b * V * 3;
    int i0 = face_vtx(faces, fid, 0, is64, V);
    int i1 = face_vtx(faces, fid, 1, is64, V);
    int i2 = face_vtx(faces, fid, 2, is64, V);
    float r1 = sqrtf(u);
    float w0 = 1.0f - r1, w1 = r1 * (1.0f - v), w2 = r1 * v;
#pragma unroll
    for (int c = 0; c < 3; ++c) {
      pts[i*3+c] = w0 * vb[i0*3+c] + w1 * vb[i1*3+c] + w2 * vb[i2*3+c];
      pnrm[i*3+c] = fnrm[((size_t)b*F + fid)*3 + c];
    }
  }
}

// ---------------- chamfer: SoA LDS + b128 broadcast + split min chains --------
// grid = 512: dir(2) x batch(4) x qchunk(64). Block = 256 thr = 4 waves.
// Lane l of wave w owns query (qc*64+l); wave w scans refs [1024w, 1024w+1024)
// in float4 groups. A-chain covers slots {0,1}, B-chain {2,3} (halved dep chain);
// A/B merge + cross-wave merge both tie-break to the smaller index.
__global__ __launch_bounds__(256) void mlk_chamfer2(
    const float* __restrict__ pred_pts, const float* __restrict__ gt_pts,
    float* __restrict__ min_p2g, float* __restrict__ min_g2p,
    int* __restrict__ idx_p2g) {
  int bid = blockIdx.x;
  int dir = bid >> 8;            // 0: pred->gt (needs idx), 1: gt->pred
  int r   = bid & 255;
  int b   = r >> 6;
  int qc  = r & 63;
  const float* qpts = dir ? gt_pts   : pred_pts;
  const float* rpts = dir ? pred_pts : gt_pts;
  int wave = threadIdx.x >> 6;
  int lane = threadIdx.x & 63;

  __shared__ float4 lpx4[kNS/4], lpy4[kNS/4], lpz4[kNS/4];  // 48 KB SoA
  float* lpx = (float*)lpx4; float* lpy = (float*)lpy4; float* lpz = (float*)lpz4;
  const float* rb = rpts + (size_t)b * kNS * 3;
  for (int i = threadIdx.x; i < kNS; i += 256) {
    lpx[i] = rb[3*i+0];
    lpy[i] = rb[3*i+1];
    lpz[i] = rb[3*i+2];
  }
  __syncthreads();

  int q  = qc * 64 + lane;
  int gi = b * kNS + q;
  float px = qpts[gi*3+0], py = qpts[gi*3+1], pz = qpts[gi*3+2];
  int j0 = wave * (kNS/4/4) * 4;      // wave*256 float4 groups
  j0 = wave * 256;
  float best; int bidx = 0;

  if (dir == 0) {
    float bA = INFINITY, bB = INFINITY; int iA = 0, iB = 0;
#pragma unroll 2
    for (int j = j0; j < j0 + 256; ++j) {
      float4 X = lpx4[j], Y = lpy4[j], Z = lpz4[j];
      int m = j << 2;
      float dx, dy, dz;
      dx = px-X.x; dy = py-Y.x; dz = pz-Z.x; float d0 = dx*dx+dy*dy+dz*dz;
      dx = px-X.y; dy = py-Y.y; dz = pz-Z.y; float d1 = dx*dx+dy*dy+dz*dz;
      dx = px-X.z; dy = py-Y.z; dz = pz-Z.z; float d2 = dx*dx+dy*dy+dz*dz;
      dx = px-X.w; dy = py-Y.w; dz = pz-Z.w; float d3 = dx*dx+dy*dy+dz*dz;
      if (d0 < bA) { bA = d0; iA = m; }
      if (d1 < bA) { bA = d1; iA = m | 1; }
      if (d2 < bB) { bB = d2; iB = m | 2; }
      if (d3 < bB) { bB = d3; iB = m | 3; }
    }
    if (bB < bA || (bB == bA && iB < iA)) { best = bB; bidx = iB; }
    else                                  { best = bA; bidx = iA; }
  } else {
    float bA = INFINITY, bB = INFINITY;
#pragma unroll 2
    for (int j = j0; j < j0 + 256; ++j) {
      float4 X = lpx4[j], Y = lpy4[j], Z = lpz4[j];
      float dx, dy, dz;
      dx = px-X.x; dy = py-Y.x; dz = pz-Z.x; float d0 = dx*dx+dy*dy+dz*dz;
      dx = px-X.y; dy = py-Y.y; dz = pz-Z.y; float d1 = dx*dx+dy*dy+dz*dz;
      dx = px-X.z; dy = py-Y.z; dz = pz-Z.z; float d2 = dx*dx+dy*dy+dz*dz;
      dx = px-X.w; dy = py-Y.w; dz = pz-Z.w; float d3 = dx*dx+dy*dy+dz*dz;
      bA = fminf(bA, fminf(d0, d1));
      bB = fminf(bB, fminf(d2, d3));
    }
    best = fminf(bA, bB);
  }

  __shared__ float cv[4][64];
  __shared__ int   ci[4][64];
  cv[wave][lane] = best; ci[wave][lane] = bidx;
  __syncthreads();
  if (wave == 0) {
    float bv = cv[0][lane]; int bi = ci[0][lane];
#pragma unroll
    for (int wv = 1; wv < 4; ++wv) {
      float v = cv[wv][lane];
      int   i = ci[wv][lane];
      if (v < bv || (v == bv && i < bi)) { bv = v; bi = i; }
    }
    if (dir == 0) { min_p2g[gi] = bv; idx_p2g[gi] = bi; }
    else          { min_g2p[gi] = bv; }
  }
}

// ---------------- loss reduction stage 1: grid-wide partials ----------------
__global__ __launch_bounds__(256) void mlk_loss_partial(
    const float* __restrict__ min_p2g, const float* __restrict__ min_g2p,
    const float* __restrict__ pred_nrm, const float* __restrict__ gt_nrm,
    const int* __restrict__ idx_p2g,
    const float* __restrict__ pverts, const int* __restrict__ pfaces,
    float* __restrict__ partial) {
  int tid = threadIdx.x;
  int gidx = blockIdx.x * 256 + tid;
  const int stride = kPB * 256;
  int is64 = faces_is64(pfaces);
  float s1 = 0.f, s2 = 0.f, sc = 0.f, se = 0.f;
  for (int i = gidx; i < kB * kNS; i += stride) {
    s1 += min_p2g[i];
    s2 += min_g2p[i];
    int b = i >> 12;
    int m = idx_p2g[i];
    m = m < 0 ? 0 : (m >= kNS ? kNS - 1 : m);
    const float* pn = pred_nrm + (size_t)i * 3;
    const float* gn = gt_nrm + ((size_t)b * kNS + m) * 3;
    sc += fabsf(pn[0]*gn[0] + pn[1]*gn[1] + pn[2]*gn[2]);
  }
  for (int e = gidx; e < kB * kFP * 3; e += stride) {
    int b = e / (kFP * 3);
    int r = e - b * kFP * 3;
    int f = r / 3, k = r - f * 3;
    int ia, ib;
    if (k == 0)      { ia = face_vtx(pfaces, f, 0, is64, kVP); ib = face_vtx(pfaces, f, 1, is64, kVP); }
    else if (k == 1) { ia = face_vtx(pfaces, f, 1, is64, kVP); ib = face_vtx(pfaces, f, 2, is64, kVP); }
    else             { ia = face_vtx(pfaces, f, 2, is64, kVP); ib = face_vtx(pfaces, f, 0, is64, kVP); }
    const float* vb = pverts + (size_t)b * kVP * 3;
    float dx = vb[ib*3+0] - vb[ia*3+0];
    float dy = vb[ib*3+1] - vb[ia*3+1];
    float dz = vb[ib*3+2] - vb[ia*3+2];
    se += dx*dx + dy*dy + dz*dz;
  }
  __shared__ float r1a[256], r2a[256], r3a[256], r4a[256];
  r1a[tid] = s1; r2a[tid] = s2; r3a[tid] = sc; r4a[tid] = se;
  __syncthreads();
  for (int off = 128; off > 0; off >>= 1) {
    if (tid < off) {
      r1a[tid] += r1a[tid+off];
      r2a[tid] += r2a[tid+off];
      r3a[tid] += r3a[tid+off];
      r4a[tid] += r4a[tid+off];
    }
    __syncthreads();
  }
  if (tid == 0) {
    partial[blockIdx.x*4+0] = r1a[0];
    partial[blockIdx.x*4+1] = r2a[0];
    partial[blockIdx.x*4+2] = r3a[0];
    partial[blockIdx.x*4+3] = r4a[0];
  }
}

// ---------------- loss reduction stage 2: combine kPB partials ----------------
__global__ __launch_bounds__(256) void mlk_loss_combine(
    const float* __restrict__ partial, float* __restrict__ out) {
  int tid = threadIdx.x;
  __shared__ float r1a[256], r2a[256], r3a[256], r4a[256];
  r1a[tid] = partial[tid*4+0];
  r2a[tid] = partial[tid*4+1];
  r3a[tid] = partial[tid*4+2];
  r4a[tid] = partial[tid*4+3];
  __syncthreads();
  for (int off = 128; off > 0; off >>= 1) {
    if (tid < off) {
      r1a[tid] += r1a[tid+off];
      r2a[tid] += r2a[tid+off];
      r3a[tid] += r3a[tid+off];
      r4a[tid] += r4a[tid+off];
    }
    __syncthreads();
  }
  if (tid == 0) {
    const float invN = 1.0f / (float)(kB * kNS);
    float chamfer = r1a[0] * invN + r2a[0] * invN;
    float nloss = 1.0f - r3a[0] * invN;
    float eloss = r4a[0] / (float)(kB * kFP * 3);
    out[0] = 1.0f * chamfer + 0.1f * nloss + 0.5f * eloss;
  }
}

// ---------------- host side ----------------
extern "C" void kernel_launch(void* const* d_in, const int* in_sizes, int n_in,
                              void* d_out, int out_size, void* d_ws, size_t ws_size,
                              hipStream_t stream) {
  const float* pverts = (const float*)d_in[0];
  const int*   pfaces = (const int*)d_in[1];
  const float* gverts = (const float*)d_in[2];
  const int*   gfaces = (const int*)d_in[3];
  float* out = (float*)d_out;

  const size_t needF =
      (size_t)kB*kFP + (size_t)kB*kFG +          // weights -> prefix (in-place)
      (size_t)kB*kFP*3 + (size_t)kB*kFG*3 +
      4*(size_t)kB*kNS*3 +
      2*(size_t)kB*kNS +
      (size_t)kPB*4 +
      (size_t)kB*kNS;                            // idx_p2g
  if (ws_size < needF * 4) {
    mlk_write_scalar<<<1, 64, 0, stream>>>(out, -1.0f);
    return;
  }

  // --- JAX threefry key chain (host, pure arithmetic) ---
  uint32_t a0 = 0u, a1 = 2u; tf2x32(0u, 42u, a0, a1);
  uint32_t b0 = 1u, b1 = 3u; tf2x32(0u, 42u, b0, b1);
  uint32_t kp0 = a0, kp1 = b0;
  uint32_t kg0 = a1, kg1 = b1;
  uint32_t kpred[6], kgt[6];
  {
    uint32_t p0 = 0u, p1 = 3u; tf2x32(kp0, kp1, p0, p1);
    uint32_t q0 = 1u, q1 = 4u; tf2x32(kp0, kp1, q0, q1);
    uint32_t r0 = 2u, r1 = 5u; tf2x32(kp0, kp1, r0, r1);
    kpred[0]=p0; kpred[1]=q0; kpred[2]=r0; kpred[3]=p1; kpred[4]=q1; kpred[5]=r1;
  }
  {
    uint32_t p0 = 0u, p1 = 3u; tf2x32(kg0, kg1, p0, p1);
    uint32_t q0 = 1u, q1 = 4u; tf2x32(kg0, kg1, q0, q1);
    uint32_t r0 = 2u, r1 = 5u; tf2x32(kg0, kg1, r0, r1);
    kgt[0]=p0; kgt[1]=q0; kgt[2]=r0; kgt[3]=p1; kgt[4]=q1; kgt[5]=r1;
  }

  // --- workspace carve (all 4-byte elements) ---
  float* ws = (float*)d_ws;
  float* pref_p   = ws; ws += kB * kFP;          // weights, then in-place prefix
  float* pref_g   = ws; ws += kB * kFG;
  float* fnrm_p   = ws; ws += kB * kFP * 3;
  float* fnrm_g   = ws; ws += kB * kFG * 3;
  float* pred_pts = ws; ws += kB * kNS * 3;
  float* gt_pts   = ws; ws += kB * kNS * 3;
  float* pred_nrm = ws; ws += kB * kNS * 3;
  float* gt_nrm   = ws; ws += kB * kNS * 3;
  float* min_p2g  = ws; ws += kB * kNS;
  float* min_g2p  = ws; ws += kB * kNS;
  float* partial  = ws; ws += kPB * 4;
  int* idx_p2g = (int*)ws; ws += kB * kNS;

  mlk_prep_faces2<<<kPREP_P + kPREP_G, 256, 0, stream>>>(
      pverts, pfaces, gverts, gfaces, pref_p, fnrm_p, pref_g, fnrm_g);

  mlk_prefix2<<<8, 256, 0, stream>>>(pref_p, pref_g);

  mlk_sample_gen<<<64, 256, 0, stream>>>(
      pverts, pfaces, pref_p, fnrm_p, pred_pts, pred_nrm,
      gverts, gfaces, pref_g, fnrm_g, gt_pts, gt_nrm,
      kpred[0], kpred[1], kpred[2], kpred[3], kpred[4], kpred[5],
      kgt[0],  kgt[1],  kgt[2],  kgt[3],  kgt[4],  kgt[5]);

  mlk_chamfer2<<<512, 256, 0, stream>>>(pred_pts, gt_pts, min_p2g, min_g2p, idx_p2g);

  mlk_loss_partial<<<kPB, 256, 0, stream>>>(min_p2g, min_g2p, pred_nrm, gt_nrm, idx_p2g,
                                            pverts, pfaces, partial);
  mlk_loss_combine<<<1, 256, 0, stream>>>(partial, out);
}